// Round 9
// baseline (660.082 us; speedup 1.0000x reference)
//
#include <hip/hip_runtime.h>
#include <hip/hip_fp16.h>
#include <math.h>

namespace {
constexpr int kB = 65536;      // rows
constexpr int kC = 300;        // cards/options dim
constexpr int kA = 32;         // archetype dim
constexpr int kCpad = 304;     // padded W rows (300..303 zeroed)
constexpr int kWSh = 36;       // W LDS row stride in HALVES (72B rows, 8B-aligned b64)
constexpr int kBlock = 512;
constexpr int kRowsPerBlock = kBlock / 16;  // 32 rows per block
constexpr int kNI = 19;        // ceil(300/16) columns owned per lane
}

// DPP row_ror reductions within each 16-lane DPP row (thread group == DPP row).
template <int kCtrl>
__device__ __forceinline__ float dpp_rot(float x) {
    int yi = __builtin_amdgcn_update_dpp(0, __builtin_bit_cast(int, x), kCtrl, 0xf, 0xf, false);
    return __builtin_bit_cast(float, yi);
}
__device__ __forceinline__ float rsum16(float x) {
    x += dpp_rot<0x128>(x);   // row_ror:8
    x += dpp_rot<0x124>(x);   // row_ror:4
    x += dpp_rot<0x122>(x);   // row_ror:2
    x += dpp_rot<0x121>(x);   // row_ror:1
    return x;
}
__device__ __forceinline__ float rmax16(float x) {
    x = fmaxf(x, dpp_rot<0x128>(x));
    x = fmaxf(x, dpp_rot<0x124>(x));
    x = fmaxf(x, dpp_rot<0x122>(x));
    x = fmaxf(x, dpp_rot<0x121>(x));
    return x;
}

// min 8 waves/EU -> allocator budget 64 VGPR -> occupancy quantum preserved
__global__ __launch_bounds__(kBlock, 8) void draftbot_kernel(
    const float* __restrict__ X,
    const float* __restrict__ W,
    float* __restrict__ out)
{
    __shared__ __half w_lds[kCpad * kWSh];   // 21,888 B

    const int tid = threadIdx.x;
    const int t = tid & 15;                 // lane within 16-thread row group
    const int grp = tid >> 4;               // row group within block
    const size_t row = (size_t)blockIdx.x * kRowsPerBlock + grp;
    const float* __restrict__ xrow = X + row * (2 * kC);

    // ---- options -> omask immediately (no persistent opts[] array) ----
    unsigned int omask = 0u;
    #pragma unroll
    for (int i = 0; i < kNI; ++i) {
        const int c = t + 16 * i;
        const float o = (c < kC) ? xrow[c] : 0.0f;
        if (o != 0.0f) omask |= (1u << i);
    }

    // ---- cards -> packed f16 pairs (values {0,1,2} are exact in f16) ----
    __half2 ch[(kNI + 1) / 2];   // 10 VGPRs instead of 19
    #pragma unroll
    for (int i = 0; i < (kNI + 1) / 2; ++i) {
        const int c0 = t + 16 * (2 * i);
        const int c1 = t + 16 * (2 * i + 1);
        const float a = (c0 < kC) ? xrow[kC + c0] : 0.0f;
        const float b = (c1 < kC) ? xrow[kC + c1] : 0.0f;
        ch[i] = __halves2half2(__float2half_rn(a), __float2half_rn(b));
    }

    // ---- stage W into LDS as f16, vectorized; zero the 4 pad rows ----
    {
        const float4* __restrict__ W4 = reinterpret_cast<const float4*>(W);
        #pragma unroll
        for (int f = tid; f < (kCpad * kA) / 4; f += kBlock) {   // 2432 float4s
            float4 v;
            if (f < (kC * kA) / 4) v = W4[f];
            else { v.x = v.y = v.z = v.w = 0.0f; }
            const int c = f >> 3;            // 8 quads per W row
            const int a4 = (f & 7) * 4;      // element offset within row
            const __half2 h01 = __halves2half2(__float2half_rn(v.x), __float2half_rn(v.y));
            const __half2 h23 = __halves2half2(__float2half_rn(v.z), __float2half_rn(v.w));
            int2 iv;
            iv.x = __builtin_bit_cast(int, h01);
            iv.y = __builtin_bit_cast(int, h23);
            *reinterpret_cast<int2*>(&w_lds[c * kWSh + a4]) = iv;   // 8B store, aligned
        }
    }
    __syncthreads();

    const __half* __restrict__ wl = w_lds + t * kWSh;  // lane base (72B stride)

    // ---- phase B: ap partial accumulation, q OUTER / i inner.
    //      f16 W x f16 cards -> v_fma_mix_f32, f32 accumulate.
    float ap[kA];
    #pragma unroll
    for (int a = 0; a < kA; ++a) ap[a] = 0.0f;
    #pragma unroll
    for (int q = 0; q < 8; ++q) {
        #pragma unroll
        for (int i = 0; i < kNI; ++i) {
            const int2 rv = *reinterpret_cast<const int2*>(wl + i * 16 * kWSh + 4 * q);
            const __half2 h01 = __builtin_bit_cast(__half2, rv.x);
            const __half2 h23 = __builtin_bit_cast(__half2, rv.y);
            const float cd = (i & 1) ? __high2float(ch[i >> 1]) : __low2float(ch[i >> 1]);
            ap[4 * q + 0] = fmaf(cd, __low2float(h01),  ap[4 * q + 0]);
            ap[4 * q + 1] = fmaf(cd, __high2float(h01), ap[4 * q + 1]);
            ap[4 * q + 2] = fmaf(cd, __low2float(h23),  ap[4 * q + 2]);
            ap[4 * q + 3] = fmaf(cd, __high2float(h23), ap[4 * q + 3]);
        }
        __builtin_amdgcn_sched_barrier(0);
    }

    // ---- 16-lane DPP reduce -> every lane holds full ap[], + bias ----
    #pragma unroll
    for (int a = 0; a < kA; ++a) ap[a] = rsum16(ap[a]) + 1.0f;

    // ---- phase D: scores, q OUTER / i inner, accumulate into sc[i] ----
    float sc[kNI];
    #pragma unroll
    for (int i = 0; i < kNI; ++i) sc[i] = 0.0f;
    #pragma unroll
    for (int q = 0; q < 8; ++q) {
        #pragma unroll
        for (int i = 0; i < kNI; ++i) {
            const int2 rv = *reinterpret_cast<const int2*>(wl + i * 16 * kWSh + 4 * q);
            const __half2 h01 = __builtin_bit_cast(__half2, rv.x);
            const __half2 h23 = __builtin_bit_cast(__half2, rv.y);
            sc[i] = fmaf(ap[4 * q + 0], __low2float(h01),  sc[i]);
            sc[i] = fmaf(ap[4 * q + 1], __high2float(h01), sc[i]);
            sc[i] = fmaf(ap[4 * q + 2], __low2float(h23),  sc[i]);
            sc[i] = fmaf(ap[4 * q + 3], __high2float(h23), sc[i]);
        }
        __builtin_amdgcn_sched_barrier(0);
    }
    #pragma unroll
    for (int i = 0; i < kNI; ++i)
        sc[i] = ((omask >> i) & 1u) ? sc[i] : 0.0f;

    // ---- row max (masked zeros participate, as in reference) ----
    float m = -INFINITY;
    #pragma unroll
    for (int i = 0; i < kNI; ++i) m = fmaxf(m, sc[i]);
    m = rmax16(m);

    // ---- sum of s * exp(x - M*s) ----
    float S = 0.f;
    #pragma unroll
    for (int i = 0; i < kNI; ++i) {
        const float x = sc[i];
        const float sg = (x > 0.f ? 1.f : 0.f) - (x < 0.f ? 1.f : 0.f);
        S += sg * __expf(fmaf(-m, sg, x));
    }
    S = rsum16(S);
    const float lse = __logf(S);

    // ---- output: s * (x - M*s - lse) ----
    float* __restrict__ orow = out + row * kC;
    #pragma unroll
    for (int i = 0; i < kNI; ++i) {
        const int c = t + 16 * i;
        if (c < kC) {
            const float x = sc[i];
            const float sg = (x > 0.f ? 1.f : 0.f) - (x < 0.f ? 1.f : 0.f);
            orow[c] = sg * (fmaf(-m, sg, x) - lse);
        }
    }
}

extern "C" void kernel_launch(void* const* d_in, const int* in_sizes, int n_in,
                              void* d_out, int out_size, void* d_ws, size_t ws_size,
                              hipStream_t stream) {
    const float* X = (const float*)d_in[0];
    const float* W = (const float*)d_in[1];
    float* out = (float*)d_out;
    dim3 grid(kB / kRowsPerBlock);   // 2048 blocks
    dim3 block(kBlock);              // 512 threads
    hipLaunchKernelGGL(draftbot_kernel, grid, block, 0, stream, X, W, out);
}

// Round 10
// 99.019 us; speedup vs baseline: 6.6662x; 6.6662x over previous
//
#include <hip/hip_runtime.h>
#include <hip/hip_fp16.h>
#include <math.h>

namespace {
constexpr int kB = 65536;      // rows
constexpr int kC = 300;        // cards/options dim
constexpr int kA = 32;         // archetype dim
constexpr int kCpad = 304;     // padded W rows (300..303 zeroed)
constexpr int kWSh = 36;       // W LDS row stride in HALVES (72B rows; lane bank (18t)%32,
                               // 16 distinct banks + b64 pairs -> conflict-free reads)
constexpr int kBlock = 512;
constexpr int kRowsPerBlock = kBlock / 16;  // 32 rows per block
constexpr int kNI = 19;        // ceil(300/16) columns owned per lane
}

// DPP row_ror reductions within each 16-lane DPP row (thread group == DPP row).
template <int kCtrl>
__device__ __forceinline__ float dpp_rot(float x) {
    int yi = __builtin_amdgcn_update_dpp(0, __builtin_bit_cast(int, x), kCtrl, 0xf, 0xf, false);
    return __builtin_bit_cast(float, yi);
}
__device__ __forceinline__ float rsum16(float x) {
    x += dpp_rot<0x128>(x);   // row_ror:8
    x += dpp_rot<0x124>(x);   // row_ror:4
    x += dpp_rot<0x122>(x);   // row_ror:2
    x += dpp_rot<0x121>(x);   // row_ror:1
    return x;
}
__device__ __forceinline__ float rmax16(float x) {
    x = fmaxf(x, dpp_rot<0x128>(x));
    x = fmaxf(x, dpp_rot<0x124>(x));
    x = fmaxf(x, dpp_rot<0x122>(x));
    x = fmaxf(x, dpp_rot<0x121>(x));
    return x;
}

__global__ __launch_bounds__(kBlock) void draftbot_kernel(
    const float* __restrict__ X,
    const float* __restrict__ W,
    float* __restrict__ out)
{
    __shared__ __half w_lds[kCpad * kWSh];   // 21,888 B

    const int tid = threadIdx.x;
    const int t = tid & 15;                 // lane within 16-thread row group
    const int grp = tid >> 4;               // row group within block
    const size_t row = (size_t)blockIdx.x * kRowsPerBlock + grp;
    const float* __restrict__ xrow = X + row * (2 * kC);

    // ---- options -> omask immediately (no persistent opts[] array) ----
    unsigned int omask = 0u;
    #pragma unroll
    for (int i = 0; i < kNI; ++i) {
        const int c = t + 16 * i;
        const float o = (c < kC) ? xrow[c] : 0.0f;
        if (o != 0.0f) omask |= (1u << i);
    }

    // ---- cards -> packed f16 pairs (values {0,1,2} are exact in f16) ----
    __half2 ch[(kNI + 1) / 2];   // 10 VGPRs instead of 19
    #pragma unroll
    for (int i = 0; i < (kNI + 1) / 2; ++i) {
        const int c0 = t + 16 * (2 * i);
        const int c1 = t + 16 * (2 * i + 1);
        const float a = (c0 < kC) ? xrow[kC + c0] : 0.0f;
        const float b = (c1 < kC) ? xrow[kC + c1] : 0.0f;
        ch[i] = __halves2half2(__float2half_rn(a), __float2half_rn(b));
    }

    // ---- stage W into LDS as f16, vectorized; zero the 4 pad rows ----
    {
        const float4* __restrict__ W4 = reinterpret_cast<const float4*>(W);
        #pragma unroll
        for (int f = tid; f < (kCpad * kA) / 4; f += kBlock) {   // 2432 float4s
            float4 v;
            if (f < (kC * kA) / 4) v = W4[f];
            else { v.x = v.y = v.z = v.w = 0.0f; }
            const int c = f >> 3;            // 8 quads per W row
            const int a4 = (f & 7) * 4;      // element offset within row
            const __half2 h01 = __halves2half2(__float2half_rn(v.x), __float2half_rn(v.y));
            const __half2 h23 = __halves2half2(__float2half_rn(v.z), __float2half_rn(v.w));
            int2 iv;
            iv.x = __builtin_bit_cast(int, h01);
            iv.y = __builtin_bit_cast(int, h23);
            *reinterpret_cast<int2*>(&w_lds[c * kWSh + a4]) = iv;   // 8B store, aligned
        }
    }
    __syncthreads();

    const __half* __restrict__ wl = w_lds + t * kWSh;  // lane base (72B stride)

    // ---- phase B: ap partials, q OUTER / i inner in chunks of 5.
    //      <=5 b64 in flight per sched region -> peak live ~56 VGPR.
    float ap[kA];
    #pragma unroll
    for (int a = 0; a < kA; ++a) ap[a] = 0.0f;
    #pragma unroll
    for (int q = 0; q < 8; ++q) {
        #pragma unroll
        for (int blk = 0; blk < 4; ++blk) {
            const int i0 = blk * 5;
            const int i1 = (blk == 3) ? kNI : (i0 + 5);
            #pragma unroll
            for (int i = i0; i < i1; ++i) {
                const int2 rv = *reinterpret_cast<const int2*>(wl + i * 16 * kWSh + 4 * q);
                const __half2 h01 = __builtin_bit_cast(__half2, rv.x);
                const __half2 h23 = __builtin_bit_cast(__half2, rv.y);
                const float cd = (i & 1) ? __high2float(ch[i >> 1]) : __low2float(ch[i >> 1]);
                ap[4 * q + 0] = fmaf(cd, __low2float(h01),  ap[4 * q + 0]);
                ap[4 * q + 1] = fmaf(cd, __high2float(h01), ap[4 * q + 1]);
                ap[4 * q + 2] = fmaf(cd, __low2float(h23),  ap[4 * q + 2]);
                ap[4 * q + 3] = fmaf(cd, __high2float(h23), ap[4 * q + 3]);
            }
            __builtin_amdgcn_sched_barrier(0);
        }
    }

    // ---- 16-lane DPP reduce -> every lane holds full ap[], + bias ----
    #pragma unroll
    for (int a = 0; a < kA; ++a) ap[a] = rsum16(ap[a]) + 1.0f;

    // ---- phase D: scores, q OUTER / i inner in chunks of 5 ----
    float sc[kNI];
    #pragma unroll
    for (int i = 0; i < kNI; ++i) sc[i] = 0.0f;
    #pragma unroll
    for (int q = 0; q < 8; ++q) {
        #pragma unroll
        for (int blk = 0; blk < 4; ++blk) {
            const int i0 = blk * 5;
            const int i1 = (blk == 3) ? kNI : (i0 + 5);
            #pragma unroll
            for (int i = i0; i < i1; ++i) {
                const int2 rv = *reinterpret_cast<const int2*>(wl + i * 16 * kWSh + 4 * q);
                const __half2 h01 = __builtin_bit_cast(__half2, rv.x);
                const __half2 h23 = __builtin_bit_cast(__half2, rv.y);
                sc[i] = fmaf(ap[4 * q + 0], __low2float(h01),  sc[i]);
                sc[i] = fmaf(ap[4 * q + 1], __high2float(h01), sc[i]);
                sc[i] = fmaf(ap[4 * q + 2], __low2float(h23),  sc[i]);
                sc[i] = fmaf(ap[4 * q + 3], __high2float(h23), sc[i]);
            }
            __builtin_amdgcn_sched_barrier(0);
        }
    }
    #pragma unroll
    for (int i = 0; i < kNI; ++i)
        sc[i] = ((omask >> i) & 1u) ? sc[i] : 0.0f;

    // ---- row max (masked zeros participate, as in reference) ----
    float m = -INFINITY;
    #pragma unroll
    for (int i = 0; i < kNI; ++i) m = fmaxf(m, sc[i]);
    m = rmax16(m);

    // ---- sum of s * exp(x - M*s) ----
    float S = 0.f;
    #pragma unroll
    for (int i = 0; i < kNI; ++i) {
        const float x = sc[i];
        const float sg = (x > 0.f ? 1.f : 0.f) - (x < 0.f ? 1.f : 0.f);
        S += sg * __expf(fmaf(-m, sg, x));
    }
    S = rsum16(S);
    const float lse = __logf(S);

    // ---- output: s * (x - M*s - lse) ----
    float* __restrict__ orow = out + row * kC;
    #pragma unroll
    for (int i = 0; i < kNI; ++i) {
        const int c = t + 16 * i;
        if (c < kC) {
            const float x = sc[i];
            const float sg = (x > 0.f ? 1.f : 0.f) - (x < 0.f ? 1.f : 0.f);
            orow[c] = sg * (fmaf(-m, sg, x) - lse);
        }
    }
}

extern "C" void kernel_launch(void* const* d_in, const int* in_sizes, int n_in,
                              void* d_out, int out_size, void* d_ws, size_t ws_size,
                              hipStream_t stream) {
    const float* X = (const float*)d_in[0];
    const float* W = (const float*)d_in[1];
    float* out = (float*)d_out;
    dim3 grid(kB / kRowsPerBlock);   // 2048 blocks
    dim3 block(kBlock);              // 512 threads
    hipLaunchKernelGGL(draftbot_kernel, grid, block, 0, stream, X, W, out);
}

// Round 11
// 56.024 us; speedup vs baseline: 11.7821x; 1.7674x over previous
//
#include <hip/hip_runtime.h>
#include <math.h>

typedef _Float16 half8 __attribute__((ext_vector_type(8)));
typedef float f32x4 __attribute__((ext_vector_type(4)));

namespace {
constexpr int kB = 65536;      // rows
constexpr int kC = 300;        // cards/options dim
constexpr int kA = 32;         // archetype dim
constexpr int kBlock = 256;    // 4 waves
constexpr int kRowsPerBlock = 64;   // 16 rows per wave
constexpr int kWTS = 328;      // f16 stride of W^T tile [32][328]; bank-step 4 -> 2-way free
constexpr int kWrS = 40;       // f16 stride of W row tile [304][40]; bank-step 20 -> 2-way free
constexpr int kApS = 40;       // per-wave ap tile stride
}

// DPP row_ror reductions within each 16-lane DPP row (quarter-wave == C-tile row group).
template <int kCtrl>
__device__ __forceinline__ float dpp_rot(float x) {
    int yi = __builtin_amdgcn_update_dpp(0, __builtin_bit_cast(int, x), kCtrl, 0xf, 0xf, false);
    return __builtin_bit_cast(float, yi);
}
__device__ __forceinline__ float rsum16(float x) {
    x += dpp_rot<0x128>(x);
    x += dpp_rot<0x124>(x);
    x += dpp_rot<0x122>(x);
    x += dpp_rot<0x121>(x);
    return x;
}
__device__ __forceinline__ float rmax16(float x) {
    x = fmaxf(x, dpp_rot<0x128>(x));
    x = fmaxf(x, dpp_rot<0x124>(x));
    x = fmaxf(x, dpp_rot<0x122>(x));
    x = fmaxf(x, dpp_rot<0x121>(x));
    return x;
}

__global__ __launch_bounds__(kBlock) void draftbot_kernel(
    const float* __restrict__ X,
    const float* __restrict__ W,
    float* __restrict__ out)
{
    __shared__ _Float16 WT[kA * kWTS];       // W^T  [a][c], c-pads zeroed   20,992 B
    __shared__ _Float16 Wr[304 * kWrS];      // W    [c][a], row-pads zeroed 24,320 B
    __shared__ _Float16 ap_s[4][16 * kApS];  // per-wave ap tile [m][a]       5,120 B

    const int tid  = threadIdx.x;
    const int lane = tid & 63;
    const int wid  = tid >> 6;
    const int lm = lane & 15;        // M/N index within fragment
    const int lq = lane >> 4;        // quarter-wave
    const int ko = lq * 8;           // K offset within 32-chunk
    const size_t r0 = (size_t)blockIdx.x * kRowsPerBlock + wid * 16;

    // ---- option bits (4 u32/lane): obit[j] bit n = options[r0+4*lq+j][16n+lm] != 0.
    //      Quarter-wave reads 64B lines; issued first so latency hides under staging.
    unsigned int obit[4];
    #pragma unroll
    for (int j = 0; j < 4; ++j) {
        const float* __restrict__ ox = X + (r0 + 4 * lq + j) * (size_t)(2 * kC);
        unsigned int b = 0;
        #pragma unroll
        for (int n = 0; n < 19; ++n) {
            const int c = 16 * n + lm;
            if (c < kC && ox[c] != 0.0f) b |= (1u << n);
        }
        obit[j] = b;
    }

    // ---- stage W into both LDS layouts (f16), coalesced f32 reads ----
    for (int e = tid; e < kC * kA; e += kBlock) {
        const int c = e >> 5;
        const int a = e & 31;
        const _Float16 h = (_Float16)W[e];
        WT[a * kWTS + c] = h;
        Wr[c * kWrS + a] = h;
    }
    for (int e = tid; e < kA * (kWTS - kC); e += kBlock) {      // zero WT c-pads (300..327)
        const int a = e / (kWTS - kC);
        const int c = kC + e % (kWTS - kC);
        WT[a * kWTS + c] = (_Float16)0.0f;
    }
    if (tid < 4 * kWrS) Wr[kC * kWrS + tid] = (_Float16)0.0f;   // zero Wr rows 300..303
    __syncthreads();

    // ---- GEMM1: ap(16x32) = cards(16x300) @ W(300x32); A from global, B from WT ----
    const float* __restrict__ crow = X + (r0 + lm) * (size_t)(2 * kC) + kC;
    f32x4 acc0 = {0.f, 0.f, 0.f, 0.f};
    f32x4 acc1 = {0.f, 0.f, 0.f, 0.f};
    #pragma unroll
    for (int s = 0; s < 9; ++s) {   // K = 0..287
        const float4 u = *reinterpret_cast<const float4*>(crow + 32 * s + ko);
        const float4 v = *reinterpret_cast<const float4*>(crow + 32 * s + ko + 4);
        const half8 Af = { (_Float16)u.x, (_Float16)u.y, (_Float16)u.z, (_Float16)u.w,
                           (_Float16)v.x, (_Float16)v.y, (_Float16)v.z, (_Float16)v.w };
        const half8 B0 = *reinterpret_cast<const half8*>(&WT[lm * kWTS + 32 * s + ko]);
        const half8 B1 = *reinterpret_cast<const half8*>(&WT[(16 + lm) * kWTS + 32 * s + ko]);
        acc0 = __builtin_amdgcn_mfma_f32_16x16x32_f16(Af, B0, acc0, 0, 0, 0);
        acc1 = __builtin_amdgcn_mfma_f32_16x16x32_f16(Af, B1, acc1, 0, 0, 0);
    }
    {   // tail K = 288..299 (A zero-padded, WT pads are zero)
        float av[8];
        #pragma unroll
        for (int j = 0; j < 8; ++j) {
            const int k = 288 + ko + j;
            av[j] = (k < kC) ? crow[k] : 0.0f;
        }
        const half8 Af = { (_Float16)av[0], (_Float16)av[1], (_Float16)av[2], (_Float16)av[3],
                           (_Float16)av[4], (_Float16)av[5], (_Float16)av[6], (_Float16)av[7] };
        const half8 B0 = *reinterpret_cast<const half8*>(&WT[lm * kWTS + 288 + ko]);
        const half8 B1 = *reinterpret_cast<const half8*>(&WT[(16 + lm) * kWTS + 288 + ko]);
        acc0 = __builtin_amdgcn_mfma_f32_16x16x32_f16(Af, B0, acc0, 0, 0, 0);
        acc1 = __builtin_amdgcn_mfma_f32_16x16x32_f16(Af, B1, acc1, 0, 0, 0);
    }

    // ---- epilogue: ap = acc + 1 -> f16 -> per-wave LDS tile (intra-wave only) ----
    _Float16* __restrict__ aps = ap_s[wid];
    #pragma unroll
    for (int j = 0; j < 4; ++j) {
        const int rr = 4 * lq + j;              // C row = 4*(lane>>4) + reg
        aps[rr * kApS + lm]      = (_Float16)(acc0[j] + 1.0f);
        aps[rr * kApS + 16 + lm] = (_Float16)(acc1[j] + 1.0f);
    }
    asm volatile("s_waitcnt lgkmcnt(0)" ::: "memory");
    __builtin_amdgcn_sched_barrier(0);
    // GEMM2 A-fragment: ap[m = lm][k = ko..ko+7], reused by all 3 passes
    const half8 A2 = *reinterpret_cast<const half8*>(&aps[lm * kApS + ko]);

    const f32x4 zz = {0.f, 0.f, 0.f, 0.f};

    // ---- pass 1: row max (masked-off elements are 0 and participate, as in ref) ----
    f32x4 mj = {0.f, 0.f, 0.f, 0.f};   // every row has zeros (option density ~5%)
    #pragma unroll
    for (int n = 0; n < 19; ++n) {
        const half8 Bn = *reinterpret_cast<const half8*>(&Wr[(16 * n + lm) * kWrS + ko]);
        const f32x4 c4 = __builtin_amdgcn_mfma_f32_16x16x32_f16(A2, Bn, zz, 0, 0, 0);
        #pragma unroll
        for (int j = 0; j < 4; ++j) {
            const float x = ((obit[j] >> n) & 1u) ? c4[j] : 0.0f;
            mj[j] = fmaxf(mj[j], x);
        }
    }
    #pragma unroll
    for (int j = 0; j < 4; ++j) mj[j] = rmax16(mj[j]);

    // ---- pass 2: S = sum of s * exp(x - M*s) ----
    f32x4 Sj = {0.f, 0.f, 0.f, 0.f};
    #pragma unroll
    for (int n = 0; n < 19; ++n) {
        const half8 Bn = *reinterpret_cast<const half8*>(&Wr[(16 * n + lm) * kWrS + ko]);
        const f32x4 c4 = __builtin_amdgcn_mfma_f32_16x16x32_f16(A2, Bn, zz, 0, 0, 0);
        #pragma unroll
        for (int j = 0; j < 4; ++j) {
            const float x = ((obit[j] >> n) & 1u) ? c4[j] : 0.0f;
            const float sg = (x > 0.f ? 1.f : 0.f) - (x < 0.f ? 1.f : 0.f);
            Sj[j] += sg * __expf(fmaf(-mj[j], sg, x));
        }
    }
    f32x4 lse;
    #pragma unroll
    for (int j = 0; j < 4; ++j) lse[j] = __logf(rsum16(Sj[j]));

    // ---- pass 3: out = s * (x - M*s - lse) ----
    #pragma unroll
    for (int n = 0; n < 19; ++n) {
        const half8 Bn = *reinterpret_cast<const half8*>(&Wr[(16 * n + lm) * kWrS + ko]);
        const f32x4 c4 = __builtin_amdgcn_mfma_f32_16x16x32_f16(A2, Bn, zz, 0, 0, 0);
        const int c = 16 * n + lm;
        if (c < kC) {
            #pragma unroll
            for (int j = 0; j < 4; ++j) {
                const float x = ((obit[j] >> n) & 1u) ? c4[j] : 0.0f;
                const float sg = (x > 0.f ? 1.f : 0.f) - (x < 0.f ? 1.f : 0.f);
                out[(r0 + 4 * lq + j) * (size_t)kC + c] = sg * (fmaf(-mj[j], sg, x) - lse[j]);
            }
        }
    }
}

extern "C" void kernel_launch(void* const* d_in, const int* in_sizes, int n_in,
                              void* d_out, int out_size, void* d_ws, size_t ws_size,
                              hipStream_t stream) {
    const float* X = (const float*)d_in[0];
    const float* W = (const float*)d_in[1];
    float* out = (float*)d_out;
    dim3 grid(kB / kRowsPerBlock);   // 1024 blocks
    dim3 block(kBlock);              // 256 threads
    hipLaunchKernelGGL(draftbot_kernel, grid, block, 0, stream, X, W, out);
}